// Round 1
// baseline (242.789 us; speedup 1.0000x reference)
//
#include <hip/hip_runtime.h>
#include <hip/hip_bf16.h>

typedef __attribute__((ext_vector_type(8))) short bf16x8;
typedef __attribute__((ext_vector_type(4))) float f32x4;

#define B_ 1024
#define T_ 256
#define C_ 384
#define H_ 64

__device__ __forceinline__ unsigned short f2bf(float f) {
  unsigned int u = __float_as_uint(f);
  return (unsigned short)((u + 0x7fffu + ((u >> 16) & 1u)) >> 16);
}

__global__ void pack_w(const float* __restrict__ Wq, const float* __restrict__ Wk,
                       const float* __restrict__ Wv, unsigned short* __restrict__ wt) {
  int id = blockIdx.x * 256 + threadIdx.x;
  if (id >= 192 * 384) return;
  int n = id / 384, k = id % 384;
  const float* W = (n < 64) ? Wq : ((n < 128) ? Wk : Wv);
  wt[id] = f2bf(W[k * 64 + (n & 63)]);
}

__launch_bounds__(256, 1)
__global__ void head_fused(const float* __restrict__ x, const float* __restrict__ cosp,
                           const float* __restrict__ sinp,
                           const unsigned short* __restrict__ wt,
                           float* __restrict__ out) {
  // LDS: Q[256][72], K[256][72] (pad 72 -> 2-way conflicts), Vt[64][264], P[4][16][264]
  __shared__ unsigned short Qlds[256 * 72];
  __shared__ unsigned short Klds[256 * 72];
  __shared__ unsigned short Vlds[64 * 264];
  __shared__ unsigned short Plds[4 * 16 * 264];

  const int tid = threadIdx.x;
  const int w = tid >> 6;        // wave 0..3
  const int lane = tid & 63;
  const int l15 = lane & 15;
  const int lq = lane >> 4;      // 0..3
  const int b = blockIdx.x;

  const float* xb = x + (size_t)b * T_ * C_;

  // ---------------- Phase 1: QKV = x @ [Wq|Wk|Wv]  (M=64 rows/wave, N=192, K=384)
  f32x4 acc[4][12];
  #pragma unroll
  for (int rt = 0; rt < 4; ++rt)
    #pragma unroll
    for (int nt = 0; nt < 12; ++nt) {
      f32x4 z = {0.f, 0.f, 0.f, 0.f};
      acc[rt][nt] = z;
    }

  for (int ks = 0; ks < 12; ++ks) {
    int k0 = ks * 32 + lq * 8;
    bf16x8 af[4];
    #pragma unroll
    for (int rt = 0; rt < 4; ++rt) {
      const float* p = xb + (w * 64 + rt * 16 + l15) * C_ + k0;
      float4 f0 = *(const float4*)p;
      float4 f1 = *(const float4*)(p + 4);
      bf16x8 a;
      a[0] = (short)f2bf(f0.x); a[1] = (short)f2bf(f0.y);
      a[2] = (short)f2bf(f0.z); a[3] = (short)f2bf(f0.w);
      a[4] = (short)f2bf(f1.x); a[5] = (short)f2bf(f1.y);
      a[6] = (short)f2bf(f1.z); a[7] = (short)f2bf(f1.w);
      af[rt] = a;
    }
    #pragma unroll
    for (int nt = 0; nt < 12; ++nt) {
      bf16x8 bf = *(const bf16x8*)(wt + (nt * 16 + l15) * C_ + k0);
      #pragma unroll
      for (int rt = 0; rt < 4; ++rt)
        acc[rt][nt] = __builtin_amdgcn_mfma_f32_16x16x32_bf16(af[rt], bf, acc[rt][nt], 0, 0, 0);
    }
  }

  // ---------------- RoPE on q (nt 0..3) and k (nt 4..7); cos table duplicated across halves
  #pragma unroll
  for (int rt = 0; rt < 4; ++rt) {
    #pragma unroll
    for (int j = 0; j < 4; ++j) {
      int t = w * 64 + rt * 16 + lq * 4 + j;
      #pragma unroll
      for (int h = 0; h < 2; ++h) {
        int c = h * 16 + l15;  // 0..31
        float cv = cosp[t * H_ + c];
        float sv = sinp[t * H_ + c];
        float a = acc[rt][h][j], bb = acc[rt][h + 2][j];
        acc[rt][h][j]     = a * cv - bb * sv;
        acc[rt][h + 2][j] = bb * cv + a * sv;
        float a2 = acc[rt][4 + h][j], b2 = acc[rt][6 + h][j];
        acc[rt][4 + h][j] = a2 * cv - b2 * sv;
        acc[rt][6 + h][j] = b2 * cv + a2 * sv;
      }
    }
  }

  // ---------------- store Q,K row-major; V transposed, all bf16
  #pragma unroll
  for (int rt = 0; rt < 4; ++rt) {
    #pragma unroll
    for (int j = 0; j < 4; ++j) {
      int t = w * 64 + rt * 16 + lq * 4 + j;
      #pragma unroll
      for (int nt = 0; nt < 4; ++nt) {
        Qlds[t * 72 + nt * 16 + l15] = f2bf(acc[rt][nt][j]);
        Klds[t * 72 + nt * 16 + l15] = f2bf(acc[rt][4 + nt][j]);
        Vlds[(nt * 16 + l15) * 264 + t] = f2bf(acc[rt][8 + nt][j]);
      }
    }
  }
  __syncthreads();

  // ---------------- Phase 2: causal attention, wave w handles ti = w, w+4, w+8, w+12
  float* ob = out + (size_t)b * T_ * H_;
  unsigned short* Pw = Plds + w * 16 * 264;

  for (int idx = 0; idx < 4; ++idx) {
    int ti = w + idx * 4;
    int t0 = ti * 16;

    bf16x8 aq[2];
    #pragma unroll
    for (int ks = 0; ks < 2; ++ks)
      aq[ks] = *(const bf16x8*)&Qlds[(t0 + l15) * 72 + ks * 32 + lq * 8];

    f32x4 sacc[16];
    #pragma unroll
    for (int si = 0; si < 16; ++si) {
      f32x4 z = {0.f, 0.f, 0.f, 0.f};
      sacc[si] = z;
    }

    #pragma unroll
    for (int si = 0; si < 16; ++si) {
      if (si <= ti) {  // causal tile skip (uniform branch)
        #pragma unroll
        for (int ks = 0; ks < 2; ++ks) {
          bf16x8 bk = *(const bf16x8*)&Klds[(si * 16 + l15) * 72 + ks * 32 + lq * 8];
          sacc[si] = __builtin_amdgcn_mfma_f32_16x16x32_bf16(aq[ks], bk, sacc[si], 0, 0, 0);
        }
      }
    }

    // scale + causal mask (covers si>ti tiles automatically: scol >= 16(ti+1) > trow)
    int trow = t0 + lq * 4;
    #pragma unroll
    for (int si = 0; si < 16; ++si) {
      #pragma unroll
      for (int j = 0; j < 4; ++j) {
        float s = sacc[si][j] * 0.125f;
        if (si * 16 + l15 > trow + j) s = -1e30f;
        sacc[si][j] = s;
      }
    }

    // softmax over row (16 lanes in quarter-wave hold one row per j)
    float rl[4];
    #pragma unroll
    for (int j = 0; j < 4; ++j) {
      float mj = -1e30f;
      #pragma unroll
      for (int si = 0; si < 16; ++si) mj = fmaxf(mj, sacc[si][j]);
      #pragma unroll
      for (int d = 1; d < 16; d <<= 1) mj = fmaxf(mj, __shfl_xor(mj, d));
      float lj = 0.0f;
      #pragma unroll
      for (int si = 0; si < 16; ++si) {
        float p = __expf(sacc[si][j] - mj);
        lj += p;
        Pw[(lq * 4 + j) * 264 + si * 16 + l15] = f2bf(p);
      }
      #pragma unroll
      for (int d = 1; d < 16; d <<= 1) lj += __shfl_xor(lj, d);
      rl[j] = 1.0f / lj;
    }

    // PV: only nk = ceil((t0+16)/32) K-steps needed (rest of P is zero)
    f32x4 oacc[4];
    #pragma unroll
    for (int nt = 0; nt < 4; ++nt) {
      f32x4 z = {0.f, 0.f, 0.f, 0.f};
      oacc[nt] = z;
    }
    int nk = (t0 + 16 + 31) >> 5;
    for (int ks = 0; ks < nk; ++ks) {
      bf16x8 ap = *(const bf16x8*)&Pw[l15 * 264 + ks * 32 + lq * 8];
      #pragma unroll
      for (int nt = 0; nt < 4; ++nt) {
        bf16x8 bv = *(const bf16x8*)&Vlds[(nt * 16 + l15) * 264 + ks * 32 + lq * 8];
        oacc[nt] = __builtin_amdgcn_mfma_f32_16x16x32_bf16(ap, bv, oacc[nt], 0, 0, 0);
      }
    }

    #pragma unroll
    for (int nt = 0; nt < 4; ++nt)
      #pragma unroll
      for (int j = 0; j < 4; ++j)
        ob[(t0 + lq * 4 + j) * H_ + nt * 16 + l15] = oacc[nt][j] * rl[j];
  }
}

extern "C" void kernel_launch(void* const* d_in, const int* in_sizes, int n_in,
                              void* d_out, int out_size, void* d_ws, size_t ws_size,
                              hipStream_t stream) {
  const float* x    = (const float*)d_in[0];
  const float* cosp = (const float*)d_in[1];
  const float* sinp = (const float*)d_in[2];
  const float* Wq   = (const float*)d_in[3];
  const float* Wk   = (const float*)d_in[4];
  const float* Wv   = (const float*)d_in[5];
  unsigned short* wt = (unsigned short*)d_ws;  // 192*384 bf16 = 147 KB
  float* out = (float*)d_out;

  pack_w<<<288, 256, 0, stream>>>(Wq, Wk, Wv, wt);
  head_fused<<<B_, 256, 0, stream>>>(x, cosp, sinp, wt, out);
}

// Round 2
// 241.260 us; speedup vs baseline: 1.0063x; 1.0063x over previous
//
#include <hip/hip_runtime.h>
#include <hip/hip_bf16.h>

typedef __attribute__((ext_vector_type(8))) short bf16x8;
typedef __attribute__((ext_vector_type(4))) float f32x4;

#define B_ 1024
#define T_ 256
#define C_ 384
#define H_ 64

__device__ __forceinline__ unsigned short f2bf(float f) {
  unsigned int u = __float_as_uint(f);
  return (unsigned short)((u + 0x7fffu + ((u >> 16) & 1u)) >> 16);
}

__global__ void pack_w(const float* __restrict__ Wq, const float* __restrict__ Wk,
                       const float* __restrict__ Wv, unsigned short* __restrict__ wt) {
  int id = blockIdx.x * 256 + threadIdx.x;
  if (id >= 192 * 384) return;
  int n = id / 384, k = id % 384;
  const float* W = (n < 64) ? Wq : ((n < 128) ? Wk : Wv);
  wt[id] = f2bf(W[k * 64 + (n & 63)]);
}

__launch_bounds__(512, 2)
__global__ void head_fused(const float* __restrict__ x, const float* __restrict__ cosp,
                           const float* __restrict__ sinp,
                           const unsigned short* __restrict__ wt,
                           float* __restrict__ out) {
  // LDS: K[256][72] (pad->2-way only), Vt[64][264], P: 8 wave-private 16x264 buffers
  // (each P buffer also stages the wave's own Q rows [32][72] before phase 2)
  __shared__ unsigned short Klds[256 * 72];
  __shared__ unsigned short Vlds[64 * 264];
  __shared__ unsigned short Plds[8 * 16 * 264];

  const int tid = threadIdx.x;
  const int w = tid >> 6;        // wave 0..7
  const int lane = tid & 63;
  const int l15 = lane & 15;
  const int lq = lane >> 4;      // 0..3
  const int b = blockIdx.x;

  const float* xb = x + (size_t)b * T_ * C_;
  const int rt[2] = {w, 15 - w};   // balanced row/attention tile ownership

  // ---------------- Phase 1: QKV = x @ [Wq|Wk|Wv]; wave handles 32 rows (2 tiles)
  f32x4 acc[2][12];
  #pragma unroll
  for (int i = 0; i < 2; ++i)
    #pragma unroll
    for (int nt = 0; nt < 12; ++nt) {
      f32x4 z = {0.f, 0.f, 0.f, 0.f};
      acc[i][nt] = z;
    }

  // depth-2 register prefetch of x
  float4 px[2][2][2];
  #pragma unroll
  for (int s = 0; s < 2; ++s)
    #pragma unroll
    for (int i = 0; i < 2; ++i) {
      const float* p = xb + (rt[i] * 16 + l15) * C_ + s * 32 + lq * 8;
      px[s][i][0] = *(const float4*)p;
      px[s][i][1] = *(const float4*)(p + 4);
    }

  #pragma unroll
  for (int ks = 0; ks < 12; ++ks) {
    const int cur = ks & 1;
    const int k0 = ks * 32 + lq * 8;

    // 1) convert current x stage (waits only on the oldest loads)
    bf16x8 af[2];
    #pragma unroll
    for (int i = 0; i < 2; ++i) {
      bf16x8 a;
      a[0] = (short)f2bf(px[cur][i][0].x); a[1] = (short)f2bf(px[cur][i][0].y);
      a[2] = (short)f2bf(px[cur][i][0].z); a[3] = (short)f2bf(px[cur][i][0].w);
      a[4] = (short)f2bf(px[cur][i][1].x); a[5] = (short)f2bf(px[cur][i][1].y);
      a[6] = (short)f2bf(px[cur][i][1].z); a[7] = (short)f2bf(px[cur][i][1].w);
      af[i] = a;
    }

    // 2) issue all 12 B-fragment loads (wt, L2-resident)
    bf16x8 bfv[12];
    #pragma unroll
    for (int nt = 0; nt < 12; ++nt)
      bfv[nt] = *(const bf16x8*)(wt + (nt * 16 + l15) * C_ + k0);

    // 3) issue x prefetch for ks+2 AFTER the bfv loads, so the MFMA waitcnt
    //    for bfv never drains the prefetch
    if (ks + 2 < 12) {
      #pragma unroll
      for (int i = 0; i < 2; ++i) {
        const float* p = xb + (rt[i] * 16 + l15) * C_ + (ks + 2) * 32 + lq * 8;
        px[cur][i][0] = *(const float4*)p;
        px[cur][i][1] = *(const float4*)(p + 4);
      }
    }

    // 4) MFMAs
    #pragma unroll
    for (int nt = 0; nt < 12; ++nt)
      #pragma unroll
      for (int i = 0; i < 2; ++i)
        acc[i][nt] = __builtin_amdgcn_mfma_f32_16x16x32_bf16(af[i], bfv[nt], acc[i][nt], 0, 0, 0);
  }

  // ---------------- RoPE on q (nt 0..3) and k (nt 4..7)
  #pragma unroll
  for (int i = 0; i < 2; ++i) {
    #pragma unroll
    for (int j = 0; j < 4; ++j) {
      int t = rt[i] * 16 + lq * 4 + j;
      #pragma unroll
      for (int h = 0; h < 2; ++h) {
        int c = h * 16 + l15;  // 0..31
        float cv = cosp[t * H_ + c];
        float sv = sinp[t * H_ + c];
        float a = acc[i][h][j], bb = acc[i][h + 2][j];
        acc[i][h][j]     = a * cv - bb * sv;
        acc[i][h + 2][j] = bb * cv + a * sv;
        float a2 = acc[i][4 + h][j], b2 = acc[i][6 + h][j];
        acc[i][4 + h][j] = a2 * cv - b2 * sv;
        acc[i][6 + h][j] = b2 * cv + a2 * sv;
      }
    }
  }

  // ---------------- stores: K row-major, V transposed (shared); Q staged into
  // the wave-private P buffer as [32][72] bf16 (2-way conflicts only)
  unsigned short* Pw = Plds + w * 16 * 264;
  #pragma unroll
  for (int i = 0; i < 2; ++i) {
    #pragma unroll
    for (int j = 0; j < 4; ++j) {
      int t = rt[i] * 16 + lq * 4 + j;
      int qr = i * 16 + lq * 4 + j;
      #pragma unroll
      for (int nt = 0; nt < 4; ++nt) {
        Pw[qr * 72 + nt * 16 + l15]    = f2bf(acc[i][nt][j]);
        Klds[t * 72 + nt * 16 + l15]   = f2bf(acc[i][4 + nt][j]);
        Vlds[(nt * 16 + l15) * 264 + t] = f2bf(acc[i][8 + nt][j]);
      }
    }
  }

  // read this wave's Q fragments back (wave-local: no barrier needed)
  bf16x8 aq[2][2];
  #pragma unroll
  for (int i = 0; i < 2; ++i)
    #pragma unroll
    for (int ks2 = 0; ks2 < 2; ++ks2)
      aq[i][ks2] = *(const bf16x8*)&Pw[(i * 16 + l15) * 72 + ks2 * 32 + lq * 8];

  __syncthreads();

  // ---------------- Phase 2: causal attention, wave w handles tiles {w, 15-w}
  float* ob = out + (size_t)b * T_ * H_;

  #pragma unroll
  for (int i = 0; i < 2; ++i) {
    const int ti = rt[i];
    const int t0 = ti * 16;

    f32x4 sacc[16];
    #pragma unroll
    for (int si = 0; si < 16; ++si) {
      f32x4 z = {0.f, 0.f, 0.f, 0.f};
      sacc[si] = z;
    }

    #pragma unroll
    for (int si = 0; si < 16; ++si) {
      if (si <= ti) {  // uniform branch (causal tile skip)
        #pragma unroll
        for (int ks2 = 0; ks2 < 2; ++ks2) {
          bf16x8 bk = *(const bf16x8*)&Klds[(si * 16 + l15) * 72 + ks2 * 32 + lq * 8];
          sacc[si] = __builtin_amdgcn_mfma_f32_16x16x32_bf16(aq[i][ks2], bk, sacc[si], 0, 0, 0);
        }
      }
    }

    // scale + causal mask
    int trow = t0 + lq * 4;
    #pragma unroll
    for (int si = 0; si < 16; ++si) {
      #pragma unroll
      for (int j = 0; j < 4; ++j) {
        float s = sacc[si][j] * 0.125f;
        if (si * 16 + l15 > trow + j) s = -1e30f;
        sacc[si][j] = s;
      }
    }

    // softmax per row (16-lane groups), P -> wave-private LDS buffer
    float rl[4];
    #pragma unroll
    for (int j = 0; j < 4; ++j) {
      float mj = -1e30f;
      #pragma unroll
      for (int si = 0; si < 16; ++si) mj = fmaxf(mj, sacc[si][j]);
      #pragma unroll
      for (int d = 1; d < 16; d <<= 1) mj = fmaxf(mj, __shfl_xor(mj, d));
      float lj = 0.0f;
      #pragma unroll
      for (int si = 0; si < 16; ++si) {
        float p = __expf(sacc[si][j] - mj);
        lj += p;
        Pw[(lq * 4 + j) * 264 + si * 16 + l15] = f2bf(p);
      }
      #pragma unroll
      for (int d = 1; d < 16; d <<= 1) lj += __shfl_xor(lj, d);
      rl[j] = 1.0f / lj;
    }

    // PV: only nk = ceil((t0+16)/32) K-steps carry nonzero P
    f32x4 oacc[4];
    #pragma unroll
    for (int nt = 0; nt < 4; ++nt) {
      f32x4 z = {0.f, 0.f, 0.f, 0.f};
      oacc[nt] = z;
    }
    int nk = (t0 + 16 + 31) >> 5;
    for (int ks2 = 0; ks2 < nk; ++ks2) {
      bf16x8 ap = *(const bf16x8*)&Pw[l15 * 264 + ks2 * 32 + lq * 8];
      #pragma unroll
      for (int nt = 0; nt < 4; ++nt) {
        bf16x8 bv = *(const bf16x8*)&Vlds[(nt * 16 + l15) * 264 + ks2 * 32 + lq * 8];
        oacc[nt] = __builtin_amdgcn_mfma_f32_16x16x32_bf16(ap, bv, oacc[nt], 0, 0, 0);
      }
    }

    #pragma unroll
    for (int nt = 0; nt < 4; ++nt)
      #pragma unroll
      for (int j = 0; j < 4; ++j)
        ob[(t0 + lq * 4 + j) * H_ + nt * 16 + l15] = oacc[nt][j] * rl[j];
  }
}

extern "C" void kernel_launch(void* const* d_in, const int* in_sizes, int n_in,
                              void* d_out, int out_size, void* d_ws, size_t ws_size,
                              hipStream_t stream) {
  const float* x    = (const float*)d_in[0];
  const float* cosp = (const float*)d_in[1];
  const float* sinp = (const float*)d_in[2];
  const float* Wq   = (const float*)d_in[3];
  const float* Wk   = (const float*)d_in[4];
  const float* Wv   = (const float*)d_in[5];
  unsigned short* wt = (unsigned short*)d_ws;  // 192*384 bf16 = 147 KB
  float* out = (float*)d_out;

  pack_w<<<288, 256, 0, stream>>>(Wq, Wk, Wv, wt);
  head_fused<<<B_, 512, 0, stream>>>(x, cosp, sinp, wt, out);
}